// Round 8
// baseline (1782.860 us; speedup 1.0000x reference)
//
#include <hip/hip_runtime.h>
#include <hip/hip_fp16.h>

typedef float  f4v __attribute__((ext_vector_type(4)));
typedef _Float16 h8v __attribute__((ext_vector_type(8)));
typedef _Float16 h4v __attribute__((ext_vector_type(4)));
typedef unsigned uv4 __attribute__((ext_vector_type(4)));

#define B_ 64
#define T_ 512
#define H_ 1024

__global__ __launch_bounds__(256) void k_transpose_cvt(const float* __restrict__ src,
                                                       _Float16* __restrict__ dst) {
  __shared__ _Float16 tile[64][72];
  int r0 = blockIdx.y * 64, c0 = blockIdx.x * 64;
  int t = threadIdx.x;
  for (int i = 0; i < 4; ++i) {
    int r = i * 16 + (t >> 4);
    int c = (t & 15) * 4;
    f4v v = *reinterpret_cast<const f4v*>(src + (long)(r0 + r) * 1024 + c0 + c);
    tile[c + 0][r] = (_Float16)v.x;
    tile[c + 1][r] = (_Float16)v.y;
    tile[c + 2][r] = (_Float16)v.z;
    tile[c + 3][r] = (_Float16)v.w;
  }
  __syncthreads();
  for (int i = 0; i < 2; ++i) {
    int rr = i * 32 + (t >> 3);
    int cc = (t & 7) * 8;
    *reinterpret_cast<h8v*>(dst + (long)(c0 + rr) * 1024 + r0 + cc) =
        *reinterpret_cast<const h8v*>(&tile[rr][cc]);
  }
}

#define SWZG(r, kh) ((((r) * 64) + ((kh) * 2)) ^ (((r) & 3) << 4))

__global__ __launch_bounds__(256) void k_gemm_xu(const float* __restrict__ x,
                                                 const _Float16* __restrict__ Ut,
                                                 const float* __restrict__ bias,
                                                 float* __restrict__ out) {
  __shared__ __attribute__((aligned(16))) unsigned char Asm[128 * 32 * 2];
  __shared__ __attribute__((aligned(16))) unsigned char Bsm[128 * 32 * 2];
  int bid = blockIdx.x;
  int nt = bid & 7, mt = bid >> 3;
  int t = threadIdx.x;
  int row = t >> 1, kc = (t & 1) * 16;
  long gA = (long)(mt * 128 + row) * 1024 + kc;
  long gB = (long)(nt * 128 + row) * 1024 + kc;
  int wid = t >> 6, lane = t & 63;
  int wr = (wid >> 1) * 64, wc = (wid & 1) * 64;
  int l15 = lane & 15, khi = (lane >> 4) * 8;

  f4v acc[4][4];
  for (int i = 0; i < 4; ++i)
    for (int j = 0; j < 4; ++j) acc[i][j] = (f4v){0.f, 0.f, 0.f, 0.f};

  f4v ra[4];
  h8v rb[2];
  {
    const float* ap = x + gA;
    ra[0] = *(const f4v*)(ap);     ra[1] = *(const f4v*)(ap + 4);
    ra[2] = *(const f4v*)(ap + 8); ra[3] = *(const f4v*)(ap + 12);
    const _Float16* bp = Ut + gB;
    rb[0] = *(const h8v*)(bp);     rb[1] = *(const h8v*)(bp + 8);
  }
  for (int kt = 0; kt < 32; ++kt) {
    h8v ah0, ah1;
    for (int j = 0; j < 4; ++j) {
      ah0[j]     = (_Float16)ra[0][j];
      ah0[j + 4] = (_Float16)ra[1][j];
      ah1[j]     = (_Float16)ra[2][j];
      ah1[j + 4] = (_Float16)ra[3][j];
    }
    *(h8v*)(Asm + SWZG(row, kc))     = ah0;
    *(h8v*)(Asm + SWZG(row, kc + 8)) = ah1;
    *(h8v*)(Bsm + SWZG(row, kc))     = rb[0];
    *(h8v*)(Bsm + SWZG(row, kc + 8)) = rb[1];
    __syncthreads();
    if (kt < 31) {
      const float* ap = x + gA + (kt + 1) * 32;
      ra[0] = *(const f4v*)(ap);     ra[1] = *(const f4v*)(ap + 4);
      ra[2] = *(const f4v*)(ap + 8); ra[3] = *(const f4v*)(ap + 12);
      const _Float16* bp = Ut + gB + (kt + 1) * 32;
      rb[0] = *(const h8v*)(bp);     rb[1] = *(const h8v*)(bp + 8);
    }
    h8v af[4], bf[4];
    for (int mi = 0; mi < 4; ++mi)
      af[mi] = *(const h8v*)(Asm + SWZG(wr + mi * 16 + l15, khi));
    for (int ni = 0; ni < 4; ++ni)
      bf[ni] = *(const h8v*)(Bsm + SWZG(wc + ni * 16 + l15, khi));
    for (int mi = 0; mi < 4; ++mi)
      for (int ni = 0; ni < 4; ++ni)
        acc[mi][ni] = __builtin_amdgcn_mfma_f32_16x16x32_f16(af[mi], bf[ni], acc[mi][ni], 0, 0, 0);
    __syncthreads();
  }
  int coff = nt * 128 + wc, roff = mt * 128 + wr;
  for (int ni = 0; ni < 4; ++ni) {
    int col = coff + ni * 16 + l15;
    float bb = bias[col];
    for (int mi = 0; mi < 4; ++mi) {
      int rbase = roff + mi * 16 + (lane >> 4) * 4;
      for (int j = 0; j < 4; ++j)
        out[(long)(rbase + j) * 1024 + col] = acc[mi][ni][j] + bb;
    }
  }
}

// ---------------------------------------------------------------------------
// Persistent scan v8.  Data path = v7-fast (plain XCD-L2 ld/st, first-touch).
// NEW signal path (fast): L2-local flag line.  32 u32 flags / cluster in ONE
// 128B line; bump = plain store of epoch to own word; wait = t0 polls line
// with 8x global_load_dwordx4 sc0 (bypass L1, read L2).  No atomics -> no
// MALL RTT, no RMW convoy.  Gated by a TWO-PHASE repeat-refresh test (a
// first-touch test cannot detect broken sc0-L1-bypass); verdict made
// cluster-uniform via the proven MALL-atomic path.  Fail -> R2 slow path.
// HW model (R3-R7): plain ld/st live in XCD L2; atomics execute at MALL;
// never mix the two on one flag.
// ---------------------------------------------------------------------------
#define SWZS(r, kh) ((((r) * 2048) + ((kh) * 2)) ^ (((r) & 7) << 4))

__global__ __launch_bounds__(256) void k_scan(const float* __restrict__ state,
                                              float* __restrict__ out,
                                              const _Float16* __restrict__ Wt,
                                              unsigned* __restrict__ ctr) {
  extern __shared__ __attribute__((aligned(16))) unsigned char smem[];
  unsigned char* Wl = smem;           // 32 x 1024 f16, swizzled (64 KB)
  unsigned char* Hl0 = smem + 65536;  // 2 x (8 x 1024 f16) = 32 KB
  __shared__ int fastflag;
  int t = threadIdx.x;
  int bid = blockIdx.x;
  int cl = bid & 7;
  int mm = bid >> 3;
  int lane = t & 63;

  unsigned* stepc  = ctr + cl * 32;          // slow-mode counter (agent atomics)
  unsigned* gbar0  = ctr + 512;              // one-time grid barriers
  unsigned* gbar1  = ctr + 544;
  unsigned* gbar2  = ctr + 576;
  unsigned* badc   = ctr + 640 + cl * 32;    // cluster bad-bit (agent atomics)
  unsigned* flagsF = ctr + 1024 + cl * 32;   // 32 flags, one 128B line
  unsigned* tst    = ctr + 2048 + bid * 32;  // per-wg test slot (own line)

  {  // stage this member's 32 Wt rows into LDS (once)
    int r = t >> 3, c8 = t & 7;
    const _Float16* wsrc = Wt + (long)(mm * 32 + r) * 1024;
    for (int j = 0; j < 16; ++j) {
      int kh = (c8 + 8 * j) * 8;
      *(h8v*)(Wl + SWZS(r, kh)) = *(const h8v*)(wsrc + kh);
    }
  }

  // ---- two-phase fast-signal test -----------------------------------------
  // Phase A: plain store -> gbar -> sc0 load (primes L1 if sc0 is broken)
  if (t == 0) {
    unsigned vA = 0xA0000000u + (unsigned)bid;
    asm volatile("global_store_dword %0, %1, off\n\ts_waitcnt vmcnt(0)"
                 :: "v"(tst), "v"(vA) : "memory");
    __hip_atomic_fetch_add(gbar0, 1u, __ATOMIC_RELAXED, __HIP_MEMORY_SCOPE_AGENT);
    while (__hip_atomic_load(gbar0, __ATOMIC_RELAXED, __HIP_MEMORY_SCOPE_AGENT) < 256u)
      __builtin_amdgcn_s_sleep(2);
  }
  __syncthreads();
  bool okA = true;
  unsigned* ps = nullptr;
  if (t < 32) {
    int peer = t * 8 + cl;  // member t of our cluster
    ps = ctr + 2048 + peer * 32;
    unsigned v;
    asm volatile("global_load_dword %0, %1, off sc0\n\ts_waitcnt vmcnt(0)"
                 : "=v"(v) : "v"(ps) : "memory");
    okA = (v == 0xA0000000u + (unsigned)(t * 8 + cl));
  }
  __syncthreads();
  // Phase B: re-store -> gbar -> sc0 load AGAIN (tests repeat-refresh)
  if (t == 0) {
    unsigned vB = 0xB0000000u + (unsigned)bid;
    asm volatile("global_store_dword %0, %1, off\n\ts_waitcnt vmcnt(0)"
                 :: "v"(tst), "v"(vB) : "memory");
    __hip_atomic_fetch_add(gbar1, 1u, __ATOMIC_RELAXED, __HIP_MEMORY_SCOPE_AGENT);
    while (__hip_atomic_load(gbar1, __ATOMIC_RELAXED, __HIP_MEMORY_SCOPE_AGENT) < 256u)
      __builtin_amdgcn_s_sleep(2);
  }
  __syncthreads();
  bool okB = true;
  if (t < 32) {
    unsigned v;
    asm volatile("global_load_dword %0, %1, off sc0\n\ts_waitcnt vmcnt(0)"
                 : "=v"(v) : "v"(ps) : "memory");
    okB = (v == 0xB0000000u + (unsigned)(t * 8 + cl));
  }
  // cluster-uniform verdict through the proven MALL path
  if (t < 32 && !(okA && okB)) {
    __hip_atomic_fetch_add(badc, 1u, __ATOMIC_RELAXED, __HIP_MEMORY_SCOPE_AGENT);
  }
  asm volatile("s_waitcnt vmcnt(0)" ::: "memory");  // bad-bit adds committed
  __syncthreads();
  if (t == 0) {
    __hip_atomic_fetch_add(gbar2, 1u, __ATOMIC_RELAXED, __HIP_MEMORY_SCOPE_AGENT);
    while (__hip_atomic_load(gbar2, __ATOMIC_RELAXED, __HIP_MEMORY_SCOPE_AGENT) < 256u)
      __builtin_amdgcn_s_sleep(2);
    fastflag = (__hip_atomic_load(badc, __ATOMIC_RELAXED, __HIP_MEMORY_SCOPE_AGENT) == 0u);
  }
  __syncthreads();
  const bool fastm = (fastflag != 0);
  // --------------------------------------------------------------------------

  int wid = t >> 6;
  int srow = t >> 5, slane = t & 31;
  long b = cl * 8 + srow;
  int l15 = lane & 15, khi8 = (lane >> 4) * 8;
  int arow = lane & 7;
  int bro = wid * 16 + l15;
  int hi = lane >> 4;
  int gcol = mm * 32 + wid * 16 + l15;
  bool prod = (wid < 2) && (hi < 2);

  for (int step = 0; step < T_; ++step) {
    unsigned char* Hb = Hl0 + (step & 1) * 16384;

    float xuv[4];
    long addr0 = 0;
    if (prod) {
      addr0 = ((long)(cl * 8 + hi * 4) * T_ + step) * 1024 + gcol;
#pragma unroll
      for (int j = 0; j < 4; ++j) xuv[j] = out[addr0 + (long)j * T_ * 1024];
    }

    if (step == 0) {
      const float* hp0 = state + b * 1024 + slane * 4;
#pragma unroll
      for (int j = 0; j < 8; ++j) {
        f4v v = *(const f4v*)(hp0 + 128 * j);
        h4v hv = {(_Float16)v.x, (_Float16)v.y, (_Float16)v.z, (_Float16)v.w};
        *(h4v*)(Hb + SWZS(srow, (slane + 32 * j) * 4)) = hv;
      }
    } else {
      // wait for h_{step-1}: all 32 flags >= step
      if (t == 0) {
        unsigned tgt = (unsigned)step;
        if (fastm) {
          for (;;) {
            uv4 f0, f1, f2, f3, f4, f5, f6, f7;
            asm volatile(
                "global_load_dwordx4 %0, %8, off sc0\n\t"
                "global_load_dwordx4 %1, %8, off offset:16 sc0\n\t"
                "global_load_dwordx4 %2, %8, off offset:32 sc0\n\t"
                "global_load_dwordx4 %3, %8, off offset:48 sc0\n\t"
                "global_load_dwordx4 %4, %8, off offset:64 sc0\n\t"
                "global_load_dwordx4 %5, %8, off offset:80 sc0\n\t"
                "global_load_dwordx4 %6, %8, off offset:96 sc0\n\t"
                "global_load_dwordx4 %7, %8, off offset:112 sc0\n\t"
                "s_waitcnt vmcnt(0)"
                : "=&v"(f0), "=&v"(f1), "=&v"(f2), "=&v"(f3),
                  "=&v"(f4), "=&v"(f5), "=&v"(f6), "=&v"(f7)
                : "v"(flagsF)
                : "memory");
            uv4 m0 = __builtin_elementwise_min(__builtin_elementwise_min(f0, f1),
                                               __builtin_elementwise_min(f2, f3));
            uv4 m1 = __builtin_elementwise_min(__builtin_elementwise_min(f4, f5),
                                               __builtin_elementwise_min(f6, f7));
            uv4 m = __builtin_elementwise_min(m0, m1);
            unsigned mn = m.x < m.y ? m.x : m.y;
            unsigned mn2 = m.z < m.w ? m.z : m.w;
            if ((mn < mn2 ? mn : mn2) >= tgt) break;
          }
        } else {
          unsigned tgt32 = 32u * (unsigned)step;
          while (__hip_atomic_load(stepc, __ATOMIC_RELAXED, __HIP_MEMORY_SCOPE_AGENT) < tgt32)
            __builtin_amdgcn_s_sleep(1);
        }
      }
      __syncthreads();

      const float* hrow = out + (b * T_ + (step - 1)) * 1024;
      if (fastm) {
#pragma unroll
        for (int j = 0; j < 8; ++j) {
          int c0 = (slane + 32 * j) * 4;
          if ((c0 >> 5) == mm) continue;  // own cols staged from regs last step
          f4v v = *(const f4v*)(hrow + c0);
          h4v hv = {(_Float16)v.x, (_Float16)v.y, (_Float16)v.z, (_Float16)v.w};
          *(h4v*)(Hb + SWZS(srow, c0)) = hv;
        }
      } else {
        const float* hp = hrow + slane * 4;
        f4v w0, w1, w2, w3, w4, w5, w6, w7;
        asm volatile(
            "global_load_dwordx4 %0, %8, off sc0 sc1\n\t"
            "global_load_dwordx4 %1, %8, off offset:512 sc0 sc1\n\t"
            "global_load_dwordx4 %2, %8, off offset:1024 sc0 sc1\n\t"
            "global_load_dwordx4 %3, %8, off offset:1536 sc0 sc1\n\t"
            "global_load_dwordx4 %4, %8, off offset:2048 sc0 sc1\n\t"
            "global_load_dwordx4 %5, %8, off offset:2560 sc0 sc1\n\t"
            "global_load_dwordx4 %6, %8, off offset:3072 sc0 sc1\n\t"
            "global_load_dwordx4 %7, %8, off offset:3584 sc0 sc1\n\t"
            "s_waitcnt vmcnt(0)"
            : "=&v"(w0), "=&v"(w1), "=&v"(w2), "=&v"(w3),
              "=&v"(w4), "=&v"(w5), "=&v"(w6), "=&v"(w7)
            : "v"(hp)
            : "memory");
        f4v wv[8] = {w0, w1, w2, w3, w4, w5, w6, w7};
#pragma unroll
        for (int j = 0; j < 8; ++j) {
          int c0 = (slane + 32 * j) * 4;
          h4v hv = {(_Float16)wv[j][0], (_Float16)wv[j][1],
                    (_Float16)wv[j][2], (_Float16)wv[j][3]};
          *(h4v*)(Hb + SWZS(srow, c0)) = hv;
        }
      }
    }
    __syncthreads();

    if (wid < 2) {
      f4v ac0 = (f4v){0.f, 0.f, 0.f, 0.f}, ac1 = ac0, ac2 = ac0, ac3 = ac0;
#pragma unroll
      for (int s = 0; s < 32; s += 4) {
        int k0 = s * 32 + khi8, k1 = k0 + 32, k2 = k0 + 64, k3 = k0 + 96;
        h8v af0 = *(const h8v*)(Hb + SWZS(arow, k0));
        h8v bf0 = *(const h8v*)(Wl + SWZS(bro, k0));
        h8v af1 = *(const h8v*)(Hb + SWZS(arow, k1));
        h8v bf1 = *(const h8v*)(Wl + SWZS(bro, k1));
        h8v af2 = *(const h8v*)(Hb + SWZS(arow, k2));
        h8v bf2 = *(const h8v*)(Wl + SWZS(bro, k2));
        h8v af3 = *(const h8v*)(Hb + SWZS(arow, k3));
        h8v bf3 = *(const h8v*)(Wl + SWZS(bro, k3));
        ac0 = __builtin_amdgcn_mfma_f32_16x16x32_f16(af0, bf0, ac0, 0, 0, 0);
        ac1 = __builtin_amdgcn_mfma_f32_16x16x32_f16(af1, bf1, ac1, 0, 0, 0);
        ac2 = __builtin_amdgcn_mfma_f32_16x16x32_f16(af2, bf2, ac2, 0, 0, 0);
        ac3 = __builtin_amdgcn_mfma_f32_16x16x32_f16(af3, bf3, ac3, 0, 0, 0);
      }
      f4v acc = (ac0 + ac1) + (ac2 + ac3);
      if (hi < 2) {
        float v0 = tanhf(acc[0] + xuv[0]);
        float v1 = tanhf(acc[1] + xuv[1]);
        float v2 = tanhf(acc[2] + xuv[2]);
        float v3 = tanhf(acc[3] + xuv[3]);
        float* p0 = out + addr0;
        float* p1 = p0 + (long)T_ * 1024;
        float* p2 = p1 + (long)T_ * 1024;
        float* p3 = p2 + (long)T_ * 1024;
        if (fastm) {
          p0[0] = v0; p1[0] = v1; p2[0] = v2; p3[0] = v3;  // plain -> XCD L2
        } else {
          asm volatile(
              "global_store_dword %0, %4, off sc0 sc1\n\t"
              "global_store_dword %1, %5, off sc0 sc1\n\t"
              "global_store_dword %2, %6, off sc0 sc1\n\t"
              "global_store_dword %3, %7, off sc0 sc1\n\t"
              "s_waitcnt vmcnt(0)"
              :: "v"(p0), "v"(p1), "v"(p2), "v"(p3),
                 "v"(v0), "v"(v1), "v"(v2), "v"(v3)
              : "memory");
        }
        if (step < T_ - 1) {
          unsigned char* Hn = Hl0 + ((step + 1) & 1) * 16384;
          int cb = gcol & ~3, co = (gcol & 3) * 2;
          int r0r = hi * 4;
          *(_Float16*)(Hn + SWZS(r0r + 0, cb) + co) = (_Float16)v0;
          *(_Float16*)(Hn + SWZS(r0r + 1, cb) + co) = (_Float16)v1;
          *(_Float16*)(Hn + SWZS(r0r + 2, cb) + co) = (_Float16)v2;
          *(_Float16*)(Hn + SWZS(r0r + 3, cb) + co) = (_Float16)v3;
        }
        if (step == T_ - 1) {
          long r = (long)cl * 8 + hi * 4;
          float* q = out + (long)B_ * T_ * 1024 + r * 1024 + gcol;
          q[0] = v0; q[1024] = v1; q[2048] = v2; q[3072] = v3;
        }
      }
    }

    if (prod) {
      asm volatile("s_waitcnt vmcnt(0)" ::: "memory");  // own h stores in L2/LLC
    }
    __syncthreads();  // wg-wide: all stores committed before the bump
    if (t == 0) {
      if (fastm) {
        unsigned e = (unsigned)(step + 1);
        asm volatile("global_store_dword %0, %1, off"
                     :: "v"(flagsF + mm), "v"(e) : "memory");
      } else {
        __hip_atomic_fetch_add(stepc, 1u, __ATOMIC_RELAXED, __HIP_MEMORY_SCOPE_AGENT);
      }
    }
  }
}

extern "C" void kernel_launch(void* const* d_in, const int* in_sizes, int n_in,
                              void* d_out, int out_size, void* d_ws, size_t ws_size,
                              hipStream_t stream) {
  const float* x     = (const float*)d_in[0];
  const float* state = (const float*)d_in[1];
  const float* W     = (const float*)d_in[2];
  const float* U     = (const float*)d_in[3];
  const float* bias  = (const float*)d_in[4];
  float* out = (float*)d_out;
  unsigned char* ws = (unsigned char*)d_ws;

  _Float16* Ut = (_Float16*)ws;
  _Float16* Wt = (_Float16*)(ws + (1u << 21));
  unsigned* ctr = (unsigned*)(ws + (1u << 22));

  hipMemsetAsync(ctr, 0, 40960, stream);

  k_transpose_cvt<<<dim3(16, 16), 256, 0, stream>>>(U, Ut);
  k_transpose_cvt<<<dim3(16, 16), 256, 0, stream>>>(W, Wt);
  k_gemm_xu<<<2048, 256, 0, stream>>>(x, Ut, bias, out);

  hipFuncSetAttribute((const void*)k_scan, hipFuncAttributeMaxDynamicSharedMemorySize, 98304);
  void* args[] = {(void*)&state, (void*)&out, (void*)&Wt, (void*)&ctr};
  hipLaunchCooperativeKernel((void*)k_scan, dim3(256), dim3(256), args, 98304, stream);
}

// Round 9
// 1663.265 us; speedup vs baseline: 1.0719x; 1.0719x over previous
//
#include <hip/hip_runtime.h>
#include <hip/hip_fp16.h>

typedef float  f4v __attribute__((ext_vector_type(4)));
typedef _Float16 h8v __attribute__((ext_vector_type(8)));
typedef _Float16 h4v __attribute__((ext_vector_type(4)));
typedef unsigned uv4 __attribute__((ext_vector_type(4)));

#define B_ 64
#define T_ 512
#define H_ 1024

__global__ __launch_bounds__(256) void k_transpose_cvt(const float* __restrict__ src,
                                                       _Float16* __restrict__ dst) {
  __shared__ _Float16 tile[64][72];
  int r0 = blockIdx.y * 64, c0 = blockIdx.x * 64;
  int t = threadIdx.x;
  for (int i = 0; i < 4; ++i) {
    int r = i * 16 + (t >> 4);
    int c = (t & 15) * 4;
    f4v v = *reinterpret_cast<const f4v*>(src + (long)(r0 + r) * 1024 + c0 + c);
    tile[c + 0][r] = (_Float16)v.x;
    tile[c + 1][r] = (_Float16)v.y;
    tile[c + 2][r] = (_Float16)v.z;
    tile[c + 3][r] = (_Float16)v.w;
  }
  __syncthreads();
  for (int i = 0; i < 2; ++i) {
    int rr = i * 32 + (t >> 3);
    int cc = (t & 7) * 8;
    *reinterpret_cast<h8v*>(dst + (long)(c0 + rr) * 1024 + r0 + cc) =
        *reinterpret_cast<const h8v*>(&tile[rr][cc]);
  }
}

#define SWZG(r, kh) ((((r) * 64) + ((kh) * 2)) ^ (((r) & 3) << 4))

__global__ __launch_bounds__(256) void k_gemm_xu(const float* __restrict__ x,
                                                 const _Float16* __restrict__ Ut,
                                                 const float* __restrict__ bias,
                                                 float* __restrict__ out) {
  __shared__ __attribute__((aligned(16))) unsigned char Asm[128 * 32 * 2];
  __shared__ __attribute__((aligned(16))) unsigned char Bsm[128 * 32 * 2];
  int bid = blockIdx.x;
  int nt = bid & 7, mt = bid >> 3;
  int t = threadIdx.x;
  int row = t >> 1, kc = (t & 1) * 16;
  long gA = (long)(mt * 128 + row) * 1024 + kc;
  long gB = (long)(nt * 128 + row) * 1024 + kc;
  int wid = t >> 6, lane = t & 63;
  int wr = (wid >> 1) * 64, wc = (wid & 1) * 64;
  int l15 = lane & 15, khi = (lane >> 4) * 8;

  f4v acc[4][4];
  for (int i = 0; i < 4; ++i)
    for (int j = 0; j < 4; ++j) acc[i][j] = (f4v){0.f, 0.f, 0.f, 0.f};

  f4v ra[4];
  h8v rb[2];
  {
    const float* ap = x + gA;
    ra[0] = *(const f4v*)(ap);     ra[1] = *(const f4v*)(ap + 4);
    ra[2] = *(const f4v*)(ap + 8); ra[3] = *(const f4v*)(ap + 12);
    const _Float16* bp = Ut + gB;
    rb[0] = *(const h8v*)(bp);     rb[1] = *(const h8v*)(bp + 8);
  }
  for (int kt = 0; kt < 32; ++kt) {
    h8v ah0, ah1;
    for (int j = 0; j < 4; ++j) {
      ah0[j]     = (_Float16)ra[0][j];
      ah0[j + 4] = (_Float16)ra[1][j];
      ah1[j]     = (_Float16)ra[2][j];
      ah1[j + 4] = (_Float16)ra[3][j];
    }
    *(h8v*)(Asm + SWZG(row, kc))     = ah0;
    *(h8v*)(Asm + SWZG(row, kc + 8)) = ah1;
    *(h8v*)(Bsm + SWZG(row, kc))     = rb[0];
    *(h8v*)(Bsm + SWZG(row, kc + 8)) = rb[1];
    __syncthreads();
    if (kt < 31) {
      const float* ap = x + gA + (kt + 1) * 32;
      ra[0] = *(const f4v*)(ap);     ra[1] = *(const f4v*)(ap + 4);
      ra[2] = *(const f4v*)(ap + 8); ra[3] = *(const f4v*)(ap + 12);
      const _Float16* bp = Ut + gB + (kt + 1) * 32;
      rb[0] = *(const h8v*)(bp);     rb[1] = *(const h8v*)(bp + 8);
    }
    h8v af[4], bf[4];
    for (int mi = 0; mi < 4; ++mi)
      af[mi] = *(const h8v*)(Asm + SWZG(wr + mi * 16 + l15, khi));
    for (int ni = 0; ni < 4; ++ni)
      bf[ni] = *(const h8v*)(Bsm + SWZG(wc + ni * 16 + l15, khi));
    for (int mi = 0; mi < 4; ++mi)
      for (int ni = 0; ni < 4; ++ni)
        acc[mi][ni] = __builtin_amdgcn_mfma_f32_16x16x32_f16(af[mi], bf[ni], acc[mi][ni], 0, 0, 0);
    __syncthreads();
  }
  int coff = nt * 128 + wc, roff = mt * 128 + wr;
  for (int ni = 0; ni < 4; ++ni) {
    int col = coff + ni * 16 + l15;
    float bb = bias[col];
    for (int mi = 0; mi < 4; ++mi) {
      int rbase = roff + mi * 16 + (lane >> 4) * 4;
      for (int j = 0; j < 4; ++j)
        out[(long)(rbase + j) * 1024 + col] = acc[mi][ni][j] + bb;
    }
  }
}

// ---------------------------------------------------------------------------
// Persistent scan v9 — single path, tagged exchange, no store-ack.
// 8 clusters x 32 members; member owns 32 cols (W slice LDS-resident).
// h exchange: hx[2][64][1024] u32 = (step<<16)|f16(h), sc0sc1 stores issued
// fire-and-forget (tags make the data self-validating -> no vmcnt ack on the
// critical path).  Signal: R2-proven relaxed-agent counter add + load-poll
// (single poller per cluster line; loads don't convoy).  Consumers bulk-load
// tagged rows (sc0sc1, proven refreshing) and retry narrowly on stale tags.
// HW model (R2-R8): plain=XCD-L2/L1-sticky, sc0sc1=LLC refreshing,
// atomics=MALL; sc0 does NOT refresh L1 -> no L2-local signaling exists.
// ---------------------------------------------------------------------------
#define SWZS(r, kh) ((((r) * 2048) + ((kh) * 2)) ^ (((r) & 7) << 4))

static __device__ __forceinline__ _Float16 lo_h(unsigned u) {
  unsigned short s = (unsigned short)u;
  _Float16 h;
  __builtin_memcpy(&h, &s, 2);
  return h;
}
static __device__ __forceinline__ unsigned pk(float f, unsigned tg) {
  _Float16 h = (_Float16)f;
  unsigned short s;
  __builtin_memcpy(&s, &h, 2);
  return (tg << 16) | (unsigned)s;
}

__global__ __launch_bounds__(256) void k_scan(const float* __restrict__ state,
                                              float* __restrict__ out,
                                              const _Float16* __restrict__ Wt,
                                              unsigned* __restrict__ hx,
                                              unsigned* __restrict__ ctr) {
  extern __shared__ __attribute__((aligned(16))) unsigned char smem[];
  unsigned char* Wl = smem;          // 32 x 1024 f16, swizzled (64 KB)
  unsigned char* Hl = smem + 65536;  // 8 x 1024 f16 (16 KB)
  int t = threadIdx.x;
  int bid = blockIdx.x;
  int cl = bid & 7;
  int mm = bid >> 3;
  int lane = t & 63;

  unsigned* stepc = ctr + cl * 32;  // per-cluster counter, own 128B line

  {  // stage this member's 32 Wt rows into LDS (once)
    int r = t >> 3, c8 = t & 7;
    const _Float16* wsrc = Wt + (long)(mm * 32 + r) * 1024;
    for (int j = 0; j < 16; ++j) {
      int kh = (c8 + 8 * j) * 8;
      *(h8v*)(Wl + SWZS(r, kh)) = *(const h8v*)(wsrc + kh);
    }
  }

  int wid = t >> 6;
  int srow = t >> 5, slane = t & 31;
  long b = cl * 8 + srow;
  int l15 = lane & 15, khi8 = (lane >> 4) * 8;
  int arow = lane & 7;
  int bro = wid * 16 + l15;
  int hi = lane >> 4;
  int gcol = mm * 32 + wid * 16 + l15;
  bool prod = (wid < 2) && (hi < 2);

  for (int step = 0; step < T_; ++step) {
    // xu prefetch (own lines; written by gemm, touched only by this thread)
    float xuv[4];
    long addr0 = 0;
    if (prod) {
      addr0 = ((long)(cl * 8 + hi * 4) * T_ + step) * 1024 + gcol;
#pragma unroll
      for (int j = 0; j < 4; ++j) xuv[j] = out[addr0 + (long)j * T_ * 1024];
    }

    if (step == 0) {
      const float* hp0 = state + b * 1024 + slane * 4;
#pragma unroll
      for (int j = 0; j < 8; ++j) {
        f4v v = *(const f4v*)(hp0 + 128 * j);
        h4v hv = {(_Float16)v.x, (_Float16)v.y, (_Float16)v.z, (_Float16)v.w};
        *(h4v*)(Hl + SWZS(srow, (slane + 32 * j) * 4)) = hv;
      }
    } else {
      // hint: all 32 members have issued their step-1 stores
      if (t == 0) {
        unsigned tgt = 32u * (unsigned)step;
        while (__hip_atomic_load(stepc, __ATOMIC_RELAXED, __HIP_MEMORY_SCOPE_AGENT) < tgt)
          __builtin_amdgcn_s_sleep(1);
      }
      __syncthreads();

      // bulk tagged load of own batch row; retry narrowly while any tag stale
      const unsigned* hp = hx + (((step - 1) & 1) * 64 + b) * 1024 + slane * 4;
      unsigned tg = (unsigned)(step - 1);
      uv4 c0, c1, c2, c3, c4, c5, c6, c7;
      for (;;) {
        asm volatile(
            "global_load_dwordx4 %0, %8, off sc0 sc1\n\t"
            "global_load_dwordx4 %1, %8, off offset:512 sc0 sc1\n\t"
            "global_load_dwordx4 %2, %8, off offset:1024 sc0 sc1\n\t"
            "global_load_dwordx4 %3, %8, off offset:1536 sc0 sc1\n\t"
            "global_load_dwordx4 %4, %8, off offset:2048 sc0 sc1\n\t"
            "global_load_dwordx4 %5, %8, off offset:2560 sc0 sc1\n\t"
            "global_load_dwordx4 %6, %8, off offset:3072 sc0 sc1\n\t"
            "global_load_dwordx4 %7, %8, off offset:3584 sc0 sc1\n\t"
            "s_waitcnt vmcnt(0)"
            : "=&v"(c0), "=&v"(c1), "=&v"(c2), "=&v"(c3),
              "=&v"(c4), "=&v"(c5), "=&v"(c6), "=&v"(c7)
            : "v"(hp)
            : "memory");
        unsigned d =
            (((c0.x >> 16) ^ tg) | ((c0.y >> 16) ^ tg) | ((c0.z >> 16) ^ tg) | ((c0.w >> 16) ^ tg)) |
            (((c1.x >> 16) ^ tg) | ((c1.y >> 16) ^ tg) | ((c1.z >> 16) ^ tg) | ((c1.w >> 16) ^ tg)) |
            (((c2.x >> 16) ^ tg) | ((c2.y >> 16) ^ tg) | ((c2.z >> 16) ^ tg) | ((c2.w >> 16) ^ tg)) |
            (((c3.x >> 16) ^ tg) | ((c3.y >> 16) ^ tg) | ((c3.z >> 16) ^ tg) | ((c3.w >> 16) ^ tg)) |
            (((c4.x >> 16) ^ tg) | ((c4.y >> 16) ^ tg) | ((c4.z >> 16) ^ tg) | ((c4.w >> 16) ^ tg)) |
            (((c5.x >> 16) ^ tg) | ((c5.y >> 16) ^ tg) | ((c5.z >> 16) ^ tg) | ((c5.w >> 16) ^ tg)) |
            (((c6.x >> 16) ^ tg) | ((c6.y >> 16) ^ tg) | ((c6.z >> 16) ^ tg) | ((c6.w >> 16) ^ tg)) |
            (((c7.x >> 16) ^ tg) | ((c7.y >> 16) ^ tg) | ((c7.z >> 16) ^ tg) | ((c7.w >> 16) ^ tg));
        if (d == 0u) break;
      }
      {
        uv4 cc[8] = {c0, c1, c2, c3, c4, c5, c6, c7};
#pragma unroll
        for (int j = 0; j < 8; ++j) {
          h4v hv = {lo_h(cc[j].x), lo_h(cc[j].y), lo_h(cc[j].z), lo_h(cc[j].w)};
          *(h4v*)(Hl + SWZS(srow, (slane + 32 * j) * 4)) = hv;
        }
      }
    }
    __syncthreads();  // Hl complete (also covers W staging at step 0)

    if (wid < 2) {
      f4v ac0 = (f4v){0.f, 0.f, 0.f, 0.f}, ac1 = ac0, ac2 = ac0, ac3 = ac0;
#pragma unroll
      for (int s = 0; s < 32; s += 4) {
        int k0 = s * 32 + khi8, k1 = k0 + 32, k2 = k0 + 64, k3 = k0 + 96;
        h8v af0 = *(const h8v*)(Hl + SWZS(arow, k0));
        h8v bf0 = *(const h8v*)(Wl + SWZS(bro, k0));
        h8v af1 = *(const h8v*)(Hl + SWZS(arow, k1));
        h8v bf1 = *(const h8v*)(Wl + SWZS(bro, k1));
        h8v af2 = *(const h8v*)(Hl + SWZS(arow, k2));
        h8v bf2 = *(const h8v*)(Wl + SWZS(bro, k2));
        h8v af3 = *(const h8v*)(Hl + SWZS(arow, k3));
        h8v bf3 = *(const h8v*)(Wl + SWZS(bro, k3));
        ac0 = __builtin_amdgcn_mfma_f32_16x16x32_f16(af0, bf0, ac0, 0, 0, 0);
        ac1 = __builtin_amdgcn_mfma_f32_16x16x32_f16(af1, bf1, ac1, 0, 0, 0);
        ac2 = __builtin_amdgcn_mfma_f32_16x16x32_f16(af2, bf2, ac2, 0, 0, 0);
        ac3 = __builtin_amdgcn_mfma_f32_16x16x32_f16(af3, bf3, ac3, 0, 0, 0);
      }
      f4v acc = (ac0 + ac1) + (ac2 + ac3);
      if (hi < 2) {
        float v0 = tanhf(acc[0] + xuv[0]);
        float v1 = tanhf(acc[1] + xuv[1]);
        float v2 = tanhf(acc[2] + xuv[2]);
        float v3 = tanhf(acc[3] + xuv[3]);
        if (step < T_ - 1) {
          // tagged release payload: fire-and-forget (tags self-validate)
          unsigned u0 = pk(v0, (unsigned)step), u1 = pk(v1, (unsigned)step);
          unsigned u2 = pk(v2, (unsigned)step), u3 = pk(v3, (unsigned)step);
          unsigned* q0 = hx + ((long)(step & 1) * 64 + cl * 8 + hi * 4) * 1024 + gcol;
          unsigned* q1 = q0 + 1024;
          unsigned* q2 = q0 + 2048;
          unsigned* q3 = q0 + 3072;
          asm volatile(
              "global_store_dword %0, %4, off sc0 sc1\n\t"
              "global_store_dword %1, %5, off sc0 sc1\n\t"
              "global_store_dword %2, %6, off sc0 sc1\n\t"
              "global_store_dword %3, %7, off sc0 sc1"
              :: "v"(q0), "v"(q1), "v"(q2), "v"(q3),
                 "v"(u0), "v"(u1), "v"(u2), "v"(u3)
              : "memory");
        }
        // f32 h -> out (plain stores, off critical path)
        out[addr0]                   = v0;
        out[addr0 + (long)T_ * 1024] = v1;
        out[addr0 + (long)T_ * 2048] = v2;
        out[addr0 + (long)T_ * 3072] = v3;
        if (step == T_ - 1) {
          long r = (long)cl * 8 + hi * 4;
          float* q = out + (long)B_ * T_ * 1024 + r * 1024 + gcol;
          q[0] = v0; q[1024] = v1; q[2048] = v2; q[3072] = v3;
        }
      }
    }

    __syncthreads();  // all tagged stores ISSUED (tags cover commit ordering)
    if (t == 0 && step < T_ - 1) {
      __hip_atomic_fetch_add(stepc, 1u, __ATOMIC_RELAXED, __HIP_MEMORY_SCOPE_AGENT);
    }
  }
}

extern "C" void kernel_launch(void* const* d_in, const int* in_sizes, int n_in,
                              void* d_out, int out_size, void* d_ws, size_t ws_size,
                              hipStream_t stream) {
  const float* x     = (const float*)d_in[0];
  const float* state = (const float*)d_in[1];
  const float* W     = (const float*)d_in[2];
  const float* U     = (const float*)d_in[3];
  const float* bias  = (const float*)d_in[4];
  float* out = (float*)d_out;
  unsigned char* ws = (unsigned char*)d_ws;

  _Float16* Ut = (_Float16*)ws;                 // 2 MB (reused as hx after gemm)
  _Float16* Wt = (_Float16*)(ws + (1u << 21));  // 2 MB
  unsigned* hx  = (unsigned*)ws;                // 512 KB, aliases Ut
  unsigned* ctr = (unsigned*)(ws + (1u << 22)); // counters

  hipMemsetAsync(ctr, 0, 4096, stream);

  k_transpose_cvt<<<dim3(16, 16), 256, 0, stream>>>(U, Ut);
  k_transpose_cvt<<<dim3(16, 16), 256, 0, stream>>>(W, Wt);
  k_gemm_xu<<<2048, 256, 0, stream>>>(x, Ut, bias, out);

  // invalidate hx tags (0xFFFF never matches a step tag); stream-ordered after gemm
  hipMemsetAsync(hx, 0xFF, 2u * 64u * 1024u * 4u, stream);

  hipFuncSetAttribute((const void*)k_scan, hipFuncAttributeMaxDynamicSharedMemorySize, 81920);
  void* args[] = {(void*)&state, (void*)&out, (void*)&Wt, (void*)&hx, (void*)&ctr};
  hipLaunchCooperativeKernel((void*)k_scan, dim3(256), dim3(256), args, 81920, stream);
}